// Round 6
// baseline (315.223 us; speedup 1.0000x reference)
//
#include <hip/hip_runtime.h>
#include <math.h>

// SpectralBias: B=1,H=16,L=2048,DH=64, M=2 modes, K=6 freqs, HIDDEN=128, OUT=9
// bias[h,i,j] = mask(i>=j) * ( sum_k G_k(h,i) cos(w_k j) + H_k(h,i) sin(w_k j)
//                              + slt(h,i)*j + cst(h,i) )
// where G_k = C_k cos(w_k i) + S_k sin(w_k i),  H_k = C_k sin(w_k i) - S_k cos(w_k i),
//       slt = softplus(y8)/64,  cst = -b0 - slt*i.

struct BiasParams {
    float omg[6];   // omega_k (np.logspace(..).astype(f32))
    float omg2[6];  // omega_k^2
    float cmn[6];   // mean_d cos(omega_k d), d in [0,2048)  (host, double prec)
    float smn[6];   // mean_d sin(omega_k d)
};

__device__ __forceinline__ float sigmoidf_(float x) { return 1.0f / (1.0f + expf(-x)); }
__device__ __forceinline__ float softplusf_(float x) {
    return fmaxf(x, 0.0f) + log1pf(expf(-fabsf(x)));   // stable, matches jax.nn.softplus
}

// ---------------- Kernel 1: per-query MLP -> {G[6], H[6], slt, cst} ----------------
// 512 blocks x 256 threads; 64 queries/block (lane = query), wave w owns hidden [32w,32w+32).
// w1/b1/w2 are read at wave-uniform addresses -> scalar loads; q lives in 64 VGPRs.
__global__ __launch_bounds__(256) void sb_coef_kernel(
    const float* __restrict__ q,  const float* __restrict__ w1,
    const float* __restrict__ b1, const float* __restrict__ w2,
    const float* __restrict__ b2, float* __restrict__ ws, BiasParams P)
{
    __shared__ float pl[256 * 13];     // layer-2 partials [4 waves][64 q][13]
    const int t    = threadIdx.x;
    const int lane = t & 63;
    const int w    = t >> 6;
    const int qid  = (blockIdx.x << 6) + lane;

    // per-lane query row -> registers
    float qv[64];
    {
        const float4* qr = (const float4*)(q + ((size_t)qid << 6));
        #pragma unroll
        for (int j = 0; j < 16; ++j) {
            float4 v = qr[j];
            qv[4*j+0] = v.x; qv[4*j+1] = v.y; qv[4*j+2] = v.z; qv[4*j+3] = v.w;
        }
    }

    const int h0 = __builtin_amdgcn_readfirstlane(w << 5);   // wave-uniform
    const float* __restrict__ w1u = w1 + (size_t)h0 * 64;

    float part[9];
    #pragma unroll
    for (int o = 0; o < 9; ++o) part[o] = 0.f;

    #pragma unroll 4
    for (int h = 0; h < 32; ++h) {
        const float* __restrict__ wr = w1u + h * 64;         // uniform row
        float a0 = 0.f, a1 = 0.f, a2 = 0.f, a3 = 0.f;
        #pragma unroll
        for (int d = 0; d < 64; d += 4) {
            a0 = fmaf(qv[d+0], wr[d+0], a0);
            a1 = fmaf(qv[d+1], wr[d+1], a1);
            a2 = fmaf(qv[d+2], wr[d+2], a2);
            a3 = fmaf(qv[d+3], wr[d+3], a3);
        }
        float a = ((a0 + a1) + (a2 + a3)) + b1[h0 + h];
        a = a * sigmoidf_(a);                                // SiLU
        #pragma unroll
        for (int o = 0; o < 9; ++o)
            part[o] = fmaf(a, w2[o * 128 + h0 + h], part[o]); // uniform scalar
    }

    #pragma unroll
    for (int o = 0; o < 9; ++o) pl[t * 13 + o] = part[o];    // stride 13: conflict-free
    __syncthreads();

    if (w == 0) {
        float y[9];
        #pragma unroll
        for (int o = 0; o < 9; ++o)
            y[o] = b2[o] + pl[lane * 13 + o] + pl[(64 + lane) * 13 + o]
                 + pl[(128 + lane) * 13 + o] + pl[(192 + lane) * 13 + o];

        float C[6], S[6];
        #pragma unroll
        for (int k = 0; k < 6; ++k) { C[k] = 0.f; S[k] = 0.f; }
        float slope = softplusf_(y[8]);

        #pragma unroll
        for (int m = 0; m < 2; ++m) {
            float p   = sigmoidf_(y[m]);
            float dst = sigmoidf_(y[2 + m]) * 2047.0f;            // delta*
            float sg  = 32.0f + sigmoidf_(y[4 + m]) * 224.0f;     // sigma
            float cm  = 0.01f * softplusf_(y[6 + m]);             // c
            float s2  = sg * sg;
            float a[6]; float asum = 0.f;
            #pragma unroll
            for (int k = 0; k < 6; ++k) { a[k] = expf(-0.5f * P.omg2[k] * s2); asum += a[k]; }
            float inv = 1.0f / (asum + 1e-9f);
            float pc  = p * cm;
            #pragma unroll
            for (int k = 0; k < 6; ++k) {
                float sn, cn;
                sincosf(P.omg[k] * dst, &sn, &cn);
                float amp = pc * (a[k] * inv);
                C[k] = fmaf(amp, cn, C[k]);
                S[k] = fmaf(amp, sn, S[k]);
            }
        }
        float b0 = 0.f;
        #pragma unroll
        for (int k = 0; k < 6; ++k) b0 += C[k] * P.cmn[k] + S[k] * P.smn[k];

        // rotate (C,S) by the row phase: per-row j-independent coefficients
        const float fi = (float)(qid & 2047);
        float G[6], Hh[6];
        #pragma unroll
        for (int k = 0; k < 6; ++k) {
            float si, ci;
            sincosf(P.omg[k] * fi, &si, &ci);
            G[k]  = fmaf(C[k], ci,  S[k] * si);
            Hh[k] = fmaf(C[k], si, -S[k] * ci);
        }
        const float slt = slope * (1.0f / 64.0f);
        const float cst = fmaf(-slt, fi, -b0);

        float* cf = ws + ((size_t)qid << 4);
        ((float4*)cf)[0] = make_float4(G[0], G[1], G[2], G[3]);
        ((float4*)cf)[1] = make_float4(G[4], G[5], Hh[0], Hh[1]);
        ((float4*)cf)[2] = make_float4(Hh[2], Hh[3], Hh[4], Hh[5]);
        ((float4*)cf)[3] = make_float4(slt, cst, 0.f, 0.f);
    }
}

// ---------------- Kernel 2: bias fill, j-strip blocks ----------------
// Grid 2048 = 16 h x 64 i-chunks(32 rows) x 2 j-strips(1024 wide).
// Thread owns 4 consecutive j; computes its 12-value Fourier basis ONCE,
// then per row: wave-uniform coef load + 14 independent FMA/elem + float4 store.
__global__ __launch_bounds__(256) void sb_bias_kernel(
    const float* __restrict__ ws, float* __restrict__ out, BiasParams P)
{
    const int bid   = blockIdx.x;
    const int strip = bid & 1;
    const int chunk = (bid >> 1) & 63;
    const int h     = bid >> 7;
    const int j0s   = strip << 10;            // 0 or 1024
    const int i0    = chunk << 5;             // 32 rows
    const int jt    = j0s + (threadIdx.x << 2);

    float4* op = (float4*)(out + (((size_t)((h << 11) + i0)) << 11) + jt);
    const ptrdiff_t rowstep = 512;            // float4s per 2048-row

    if (i0 + 31 < j0s) {                      // fully above diagonal: zero-fill
        const float4 z = make_float4(0.f, 0.f, 0.f, 0.f);
        #pragma unroll 8
        for (int r = 0; r < 32; ++r) { *op = z; op += rowstep; }
        return;
    }

    // per-thread Fourier basis at its 4 j's (amortized over 32 rows)
    float cb[4][6], sb[4][6];
    #pragma unroll
    for (int s = 0; s < 4; ++s) {
        const float fj = (float)(jt + s);
        #pragma unroll
        for (int k = 0; k < 6; ++k) sincosf(P.omg[k] * fj, &sb[s][k], &cb[s][k]);
    }
    const float fj0 = (float)jt;
    const float* cf = ws + (((size_t)((h << 11) + i0)) << 4);   // uniform per row

    if (i0 >= j0s + 1023) {
        // fully interior: no mask select
        for (int r = 0; r < 32; ++r) {
            const float4 a0 = ((const float4*)cf)[0];
            const float4 a1 = ((const float4*)cf)[1];
            const float4 a2 = ((const float4*)cf)[2];
            const float4 a3 = ((const float4*)cf)[3];
            const float G[6] = {a0.x, a0.y, a0.z, a0.w, a1.x, a1.y};
            const float H[6] = {a1.z, a1.w, a2.x, a2.y, a2.z, a2.w};
            const float slt = a3.x, cst = a3.y;
            float res[4];
            #pragma unroll
            for (int s = 0; s < 4; ++s) {
                float acc = fmaf(slt, fj0 + (float)s, cst);
                #pragma unroll
                for (int k = 0; k < 6; ++k) {
                    acc = fmaf(G[k], cb[s][k], acc);
                    acc = fmaf(H[k], sb[s][k], acc);
                }
                res[s] = acc;
            }
            *op = make_float4(res[0], res[1], res[2], res[3]);
            op += rowstep; cf += 16;
        }
    } else {
        // diagonal crosses this block: per-element mask
        for (int r = 0; r < 32; ++r) {
            const float4 a0 = ((const float4*)cf)[0];
            const float4 a1 = ((const float4*)cf)[1];
            const float4 a2 = ((const float4*)cf)[2];
            const float4 a3 = ((const float4*)cf)[3];
            const float G[6] = {a0.x, a0.y, a0.z, a0.w, a1.x, a1.y};
            const float H[6] = {a1.z, a1.w, a2.x, a2.y, a2.z, a2.w};
            const float slt = a3.x, cst = a3.y;
            const int di = (i0 + r) - jt;     // elements s<=di are unmasked
            float res[4];
            #pragma unroll
            for (int s = 0; s < 4; ++s) {
                float acc = fmaf(slt, fj0 + (float)s, cst);
                #pragma unroll
                for (int k = 0; k < 6; ++k) {
                    acc = fmaf(G[k], cb[s][k], acc);
                    acc = fmaf(H[k], sb[s][k], acc);
                }
                res[s] = (s <= di) ? acc : 0.f;
            }
            *op = make_float4(res[0], res[1], res[2], res[3]);
            op += rowstep; cf += 16;
        }
    }
}

extern "C" void kernel_launch(void* const* d_in, const int* in_sizes, int n_in,
                              void* d_out, int out_size, void* d_ws, size_t ws_size,
                              hipStream_t stream) {
    const float* q  = (const float*)d_in[0];
    const float* w1 = (const float*)d_in[1];
    const float* b1 = (const float*)d_in[2];
    const float* w2 = (const float*)d_in[3];
    const float* b2 = (const float*)d_in[4];
    float* out = (float*)d_out;
    float* ws  = (float*)d_ws;

    BiasParams P;
    const double l0 = log10(2.0 * M_PI / 1.0e6);     // log10(w_min)
    const double l1 = log10(2.0 * M_PI / 2048.0);    // log10(w_max)
    for (int k = 0; k < 6; ++k) {
        double e  = l0 + (l1 - l0) * ((double)k / 5.0);
        float  wf = (float)pow(10.0, e);             // matches np.logspace(...).astype(f32)
        P.omg[k]  = wf;
        P.omg2[k] = wf * wf;
        double cm = 0.0, sm = 0.0;
        for (int d = 0; d < 2048; ++d) { cm += cos((double)wf * d); sm += sin((double)wf * d); }
        P.cmn[k] = (float)(cm / 2048.0);
        P.smn[k] = (float)(sm / 2048.0);
    }

    sb_coef_kernel<<<512, 256, 0, stream>>>(q, w1, b1, w2, b2, ws, P);
    sb_bias_kernel<<<2048, 256, 0, stream>>>(ws, out, P);
}